// Round 4
// baseline (1465.474 us; speedup 1.0000x reference)
//
#include <hip/hip_runtime.h>
#include <cstdint>
#include <cstddef>

// ---------------------------------------------------------------------------
// Problem constants
// ---------------------------------------------------------------------------
constexpr int NB = 256;   // batch
constexpr int NC = 512;   // c_length
constexpr int NL = 16;    // lattice side
constexpr int NFS = 15;   // neighborhood size

#define PARTITIONABLE 1

// ---------------------------------------------------------------------------
// Threefry2x32-20 (JAX-compatible), usable at compile time and on device
// ---------------------------------------------------------------------------
struct TFOut { uint32_t a, b; };

__host__ __device__ constexpr uint32_t rotl32(uint32_t x, int d) {
  return (x << d) | (x >> (32 - d));
}

__host__ __device__ constexpr TFOut tf2x32(uint32_t k0, uint32_t k1,
                                           uint32_t x0, uint32_t x1) {
  uint32_t k2 = k0 ^ k1 ^ 0x1BD11BDAu;
  x0 += k0; x1 += k1;
  const int R0[4] = {13, 15, 26, 6};
  const int R1[4] = {17, 29, 16, 24};
  for (int i = 0; i < 4; i++) { x0 += x1; x1 = rotl32(x1, R0[i]); x1 ^= x0; }
  x0 += k1; x1 += k2 + 1u;
  for (int i = 0; i < 4; i++) { x0 += x1; x1 = rotl32(x1, R1[i]); x1 ^= x0; }
  x0 += k2; x1 += k0 + 2u;
  for (int i = 0; i < 4; i++) { x0 += x1; x1 = rotl32(x1, R0[i]); x1 ^= x0; }
  x0 += k0; x1 += k1 + 3u;
  for (int i = 0; i < 4; i++) { x0 += x1; x1 = rotl32(x1, R1[i]); x1 ^= x0; }
  x0 += k1; x1 += k2 + 4u;
  for (int i = 0; i < 4; i++) { x0 += x1; x1 = rotl32(x1, R0[i]); x1 ^= x0; }
  x0 += k2; x1 += k0 + 5u;
  return TFOut{x0, x1};
}

struct SubKeys { uint32_t v[288]; };

constexpr SubKeys make_subkeys() {
  SubKeys s{};
  uint32_t k0 = 0u, k1 = 1234u;
  for (int t = 0; t < 144; t++) {
#if PARTITIONABLE
    TFOut nk = tf2x32(k0, k1, 0u, 0u);
    TFOut sk = tf2x32(k0, k1, 0u, 1u);
    s.v[2 * t] = sk.a; s.v[2 * t + 1] = sk.b;
    k0 = nk.a; k1 = nk.b;
#else
    TFOut p0 = tf2x32(k0, k1, 0u, 2u);
    TFOut p1 = tf2x32(k0, k1, 1u, 3u);
    s.v[2 * t] = p0.b; s.v[2 * t + 1] = p1.b;
    k0 = p0.a; k1 = p1.a;
#endif
  }
  return s;
}

__constant__ SubKeys SUBKEYS = make_subkeys();

__device__ __forceinline__ float gumbel_from_bits(uint32_t bits) {
  uint32_t ub = (bits >> 9) | 0x3f800000u;
  float f = __uint_as_float(ub) - 1.0f;
  float u = (f == 0.0f) ? 1.17549435e-38f : f;
  float inner = logf(u);
  float outer = logf(-inner);
  return -outer;
}

// ---------------------------------------------------------------------------
// Kernel 0: init workspace + outputs
// ---------------------------------------------------------------------------
__global__ __launch_bounds__(256) void setup_kernel(
    const float* __restrict__ u_in, const int* __restrict__ v_in,
    float* __restrict__ h0buf, float* __restrict__ cbuf,
    float* __restrict__ u_cur, int* __restrict__ v_cur,
    float* __restrict__ out_soft, float* __restrict__ out_u,
    float* __restrict__ out_v) {
  int idx = blockIdx.x * 256 + threadIdx.x;
  h0buf[idx] = 0.0f;                       // 2 parities x [4][NB][NC]
  if (idx < 4 * NB * NC) cbuf[idx] = 0.0f;
  if (idx < NB * NL * NL) {
    float uv = u_in[idx];
    int vv = v_in[idx];
    u_cur[idx] = uv;
    v_cur[idx] = vv;
    out_u[idx] = uv;
    out_v[idx] = (float)vv;
  }
  if (idx < NB * NL * NL * 2) out_soft[idx] = 0.0f;
}

// ---------------------------------------------------------------------------
// Transpose kernels (run once per launch; feed the outer-product GEMMs)
// in[R][C] -> out[C][R], R,C multiples of 64
// FIX vs round 3: 64x64 tile = 4096 elems needs 16 iterations of 256 threads
// (was 4 -> three quarters of every tile left as poison).
// ---------------------------------------------------------------------------
__global__ __launch_bounds__(256) void transpose_kernel(
    const float* __restrict__ in, float* __restrict__ out, int R, int C) {
  __shared__ float tile[64][65];
  int tc = blockIdx.x % (C >> 6);
  int tr = blockIdx.x / (C >> 6);
  int tid = threadIdx.x;
  for (int it = 0; it < 16; it++) {
    int idx = it * 256 + tid;
    int rr = idx >> 6, cc = idx & 63;
    tile[rr][cc] = in[(size_t)(tr * 64 + rr) * C + tc * 64 + cc];
  }
  __syncthreads();
  for (int it = 0; it < 16; it++) {
    int idx = it * 256 + tid;
    int rr = idx >> 6, cc = idx & 63;
    out[(size_t)(tc * 64 + rr) * R + tr * 64 + cc] = tile[cc][rr];
  }
}

// wih[2048][16] -> rows 512..527 of whhT[528][2048]
__global__ __launch_bounds__(256) void wih_t_kernel(
    const float* __restrict__ wih, float* __restrict__ whhT) {
  int idx = blockIdx.x * 256 + threadIdx.x;   // 32768
  int n = idx >> 11, cg = idx & 2047;
  whhT[(size_t)(512 + n) * 2048 + cg] = wih[cg * 16 + n];
}

// ---------------------------------------------------------------------------
// Kernel 1: WD[n][c] = W1 · (emb[n,1]-emb[n,0]);  A0 = W1 · Σ emb[n,0] + b1
// ---------------------------------------------------------------------------
__global__ __launch_bounds__(256) void wd_kernel(
    const float* __restrict__ emb, const float* __restrict__ w1,
    const float* __restrict__ b1, float* __restrict__ WD,
    float* __restrict__ A0v) {
  __shared__ double dvec[NC];
  int n = blockIdx.x, tid = threadIdx.x;
  for (int k = tid; k < NC; k += 256) {
    if (n < NFS) {
      dvec[k] = (double)emb[(n * 2 + 1) * NC + k] - (double)emb[(n * 2) * NC + k];
    } else {
      double s = 0.0;
      for (int nn = 0; nn < NFS; nn++) s += (double)emb[(nn * 2) * NC + k];
      dvec[k] = s;
    }
  }
  __syncthreads();
  for (int c = tid; c < NC; c += 256) {
    double acc = 0.0;
    const float* wrow = w1 + (size_t)c * NC;
    for (int k = 0; k < NC; k++) acc += dvec[k] * (double)wrow[k];
    if (n < NFS) WD[n * NC + c] = (float)acc;
    else         A0v[c] = (float)(acc + (double)b1[c]);
  }
}

// ---------------------------------------------------------------------------
// Kernel 2: LSTM sector event — outer-product formulation.
// lane = output column (coalesced whhT loads, double-buffered registers);
// h[row][k] is wave-uniform -> scalar loads, SGPR operand in v_fma.
// Tile: 8 rows x 64 cols per wave; 4 waves (= 4 gates) per block.
// grid = 96 rowgroups * 8 colgroups = 768 blocks (exactly 3 blocks/CU).
// ---------------------------------------------------------------------------
__global__ __launch_bounds__(256) void lstm_event_kernel(
    const float* __restrict__ u_cur, const float* __restrict__ whhT,
    const float* __restrict__ bih, const float* __restrict__ bhh,
    const float* __restrict__ h_in,   // [s*256+b][512], s in 0..2
    float* __restrict__ h_out, float* __restrict__ cbuf, int col0) {
  int bx = blockIdx.x;
  int cg = bx & 7, rg = bx >> 3;
  int tid = threadIdx.x;
  int g = tid >> 6, lane = tid & 63;
  int colgate = g * 512 + cg * 64 + lane;
  int row0 = rg * 8;

  float bias = bih[colgate] + bhh[colgate];
  float acc[8];
#pragma unroll
  for (int r = 0; r < 8; r++) acc[r] = bias;

  const float* hb = h_in + (size_t)row0 * NC;
  float wA[32], wB[32];
#pragma unroll
  for (int kk = 0; kk < 32; kk++)
    wA[kk] = whhT[(size_t)kk * 2048 + colgate];

#pragma unroll 1
  for (int k0 = 0; k0 < 512; k0 += 64) {
#pragma unroll
    for (int kk = 0; kk < 32; kk++)
      wB[kk] = whhT[(size_t)(k0 + 32 + kk) * 2048 + colgate];
#pragma unroll
    for (int r = 0; r < 8; r++) {
      const float* hr = hb + (size_t)r * NC + k0;
#pragma unroll
      for (int kk = 0; kk < 32; kk++)
        acc[r] = fmaf(hr[kk], wA[kk], acc[r]);
    }
    if (k0 + 64 < 512) {
#pragma unroll
      for (int kk = 0; kk < 32; kk++)
        wA[kk] = whhT[(size_t)(k0 + 64 + kk) * 2048 + colgate];
    }
#pragma unroll
    for (int r = 0; r < 8; r++) {
      const float* hr = hb + (size_t)r * NC + k0 + 32;
#pragma unroll
      for (int kk = 0; kk < 32; kk++)
        acc[r] = fmaf(hr[kk], wB[kk], acc[r]);
    }
  }

  // uv @ wih^T : 16 extra k-steps (wihT = rows 512..527 of whhT)
  {
    int s = row0 >> 8;           // rows in a group share s (256 % 8 == 0)
    int b0 = row0 & 255;
    float wi[16];
#pragma unroll
    for (int n = 0; n < 16; n++)
      wi[n] = whhT[(size_t)(512 + n) * 2048 + colgate];
#pragma unroll
    for (int r = 0; r < 8; r++) {
      const float* ur = u_cur + (b0 + r) * 256 + s * 64 + col0;
#pragma unroll
      for (int n = 0; n < 16; n++)
        acc[r] = fmaf(ur[(n >> 2) * 16 + (n & 3)], wi[n], acc[r]);
    }
  }

  // epilogue: gate exchange + nonlinearity
  __shared__ float xch[4][8][68];
#pragma unroll
  for (int r = 0; r < 8; r++) xch[g][r][lane] = acc[r];
  __syncthreads();
  {
    int r = tid >> 5;               // 0..7
    int c2 = (tid & 31) * 2;        // 0,2,..,62
    int row = row0 + r;
    size_t off = (size_t)row * NC + cg * 64 + c2;
    float2 cold = *(const float2*)&cbuf[off];
    float cold2[2] = {cold.x, cold.y};
    float cn[2], hn[2];
#pragma unroll
    for (int q = 0; q < 2; q++) {
      float gi = xch[0][r][c2 + q], gf = xch[1][r][c2 + q];
      float gg = xch[2][r][c2 + q], go = xch[3][r][c2 + q];
      float si = 1.0f / (1.0f + expf(-gi));
      float sf = 1.0f / (1.0f + expf(-gf));
      float tg = tanhf(gg);
      float so = 1.0f / (1.0f + expf(-go));
      float c_ = sf * cold2[q] + si * tg;
      cn[q] = c_;
      hn[q] = so * tanhf(c_);
    }
    *(float2*)&cbuf[off] = make_float2(cn[0], cn[1]);
    *(float2*)&h_out[off] = make_float2(hn[0], hn[1]);
  }
}

// ---------------------------------------------------------------------------
// Kernel 3: H = W1 · h0  (outer-product, w1T pre-transposed)
// grid = 64 rowgroups(4 rows) * 8 colgroups = 512 one-wave blocks.
// ---------------------------------------------------------------------------
__global__ __launch_bounds__(64) void w1h0_kernel(
    const float* __restrict__ h_in, const float* __restrict__ w1T,
    float* __restrict__ Hbuf) {
  int bx = blockIdx.x;
  int cg = bx & 7, rg = bx >> 3;
  int lane = threadIdx.x;
  int c = cg * 64 + lane;
  int row0 = rg * 4;

  float acc[4] = {0.f, 0.f, 0.f, 0.f};
  const float* hb = h_in + (size_t)row0 * NC;
  float wA[32], wB[32];
#pragma unroll
  for (int kk = 0; kk < 32; kk++) wA[kk] = w1T[(size_t)kk * NC + c];

#pragma unroll 1
  for (int k0 = 0; k0 < 512; k0 += 64) {
#pragma unroll
    for (int kk = 0; kk < 32; kk++)
      wB[kk] = w1T[(size_t)(k0 + 32 + kk) * NC + c];
#pragma unroll
    for (int r = 0; r < 4; r++) {
      const float* hr = hb + (size_t)r * NC + k0;
#pragma unroll
      for (int kk = 0; kk < 32; kk++)
        acc[r] = fmaf(hr[kk], wA[kk], acc[r]);
    }
    if (k0 + 64 < 512) {
#pragma unroll
      for (int kk = 0; kk < 32; kk++)
        wA[kk] = w1T[(size_t)(k0 + 64 + kk) * NC + c];
    }
#pragma unroll
    for (int r = 0; r < 4; r++) {
      const float* hr = hb + (size_t)r * NC + k0 + 32;
#pragma unroll
      for (int kk = 0; kk < 32; kk++)
        acc[r] = fmaf(hr[kk], wB[kk], acc[r]);
    }
  }
#pragma unroll
  for (int r = 0; r < 4; r++)
    Hbuf[(size_t)(row0 + r) * NC + c] = acc[r];
}

// ---------------------------------------------------------------------------
// Kernel 4: 16-pixel autoregressive block (register version) —
// single Hbuf read instead of 8 Hpart partials.
// ---------------------------------------------------------------------------
__global__ __launch_bounds__(64) void pixel_kernel(
    const float* __restrict__ WD, const float* __restrict__ A0v,
    const float* __restrict__ Hbuf, const float* __restrict__ w2,
    const float* __restrict__ b2, float* __restrict__ u_cur,
    int* __restrict__ v_cur, float* __restrict__ out_soft,
    float* __restrict__ out_u, float* __restrict__ out_v,
    int si, int sj, int t_base) {
  int b = blockIdx.x, lane = threadIdx.x;
  __shared__ float gum[32];

  int widx = (lane < 49) ? lane : 48;
  int vv = v_cur[b * 256 + (si + 1 + widx / 7) * 16 + (sj + 1 + widx % 7)];
  unsigned long long mask = __ballot((lane < 49) && (vv != 0));

  if (lane < 32) {
    int t = t_base + (lane >> 1);
    uint32_t sk0 = SUBKEYS.v[2 * t], sk1 = SUBKEYS.v[2 * t + 1];
    uint32_t bits;
#if PARTITIONABLE
    TFOut o = tf2x32(sk0, sk1, 0u, (uint32_t)(2 * b + (lane & 1)));
    bits = o.a ^ o.b;
#else
    uint32_t f = (uint32_t)(2 * b + (lane & 1));
    if (f < 256u) { TFOut o = tf2x32(sk0, sk1, f, f + 256u); bits = o.a; }
    else          { TFOut o = tf2x32(sk0, sk1, f - 256u, f); bits = o.b; }
#endif
    gum[lane] = gumbel_from_bits(bits);
  }

  float wdreg[NFS][8];
#pragma unroll
  for (int n = 0; n < NFS; n++)
#pragma unroll
    for (int r = 0; r < 8; r++) wdreg[n][r] = WD[n * NC + lane + 64 * r];

  float w2r0[8], w2r1[8];
#pragma unroll
  for (int r = 0; r < 8; r++) {
    w2r0[r] = w2[lane + 64 * r];
    w2r1[r] = w2[NC + lane + 64 * r];
  }
  double b20 = (double)b2[0], b21 = (double)b2[1];

  float base[8];
#pragma unroll
  for (int r = 0; r < 8; r++) {
    int c = lane + 64 * r;
    base[r] = A0v[c] + Hbuf[(size_t)b * NC + c];
  }
  __syncthreads();

#pragma unroll 1
  for (int ii = 0; ii < 4; ii++) {
#pragma unroll 1
    for (int jj = 0; jj < 4; jj++) {
      int bofs = ii * 7 + jj;
      float acc[8];
#pragma unroll
      for (int r = 0; r < 8; r++) acc[r] = base[r];
#pragma unroll
      for (int n = 0; n < NFS; n++) {
        const int OFF = (n / 4) * 7 + (n % 4);
        float pf = (float)((unsigned)((mask >> (bofs + OFF)) & 1ull));
#pragma unroll
        for (int r = 0; r < 8; r++) acc[r] = fmaf(pf, wdreg[n][r], acc[r]);
      }
      double d0 = 0.0, d1 = 0.0;
#pragma unroll
      for (int r = 0; r < 8; r++) {
        float z = fmaxf(acc[r], 0.0f);
        d0 += (double)z * (double)w2r0[r];
        d1 += (double)z * (double)w2r1[r];
      }
#pragma unroll
      for (int off = 32; off > 0; off >>= 1) {
        d0 += __shfl_xor(d0, off, 64);
        d1 += __shfl_xor(d1, off, 64);
      }
      float r0 = (float)(d0 + b20);
      float r1 = (float)(d1 + b21);
      float m = fmaxf(r0, r1);
      float s0 = r0 - m, s1 = r1 - m;
      float lse = logf(expf(s0) + expf(s1));
      float l0 = s0 - lse, l1 = s1 - lse;
      int pidx = ii * 4 + jj;
      float a0 = l0 + gum[2 * pidx];
      float a1 = l1 + gum[2 * pidx + 1];
      int samp = (a1 > a0) ? 1 : 0;
      int tbit = bofs + 24;
      mask = (mask & ~(1ull << tbit)) | ((unsigned long long)samp << tbit);
      if (lane == 0) {
        int pr = si + ii + 4, pc = sj + jj + 4;
        size_t so = ((size_t)(b * 16 + pr) * 16 + pc) * 2;
        out_soft[so] = l0;
        out_soft[so + 1] = l1;
        int po = b * 256 + pr * 16 + pc;
        float fs = (float)samp;
        u_cur[po] = fs;
        v_cur[po] = samp;
        out_u[po] = fs;
        out_v[po] = fs;
      }
    }
  }
}

// ---------------------------------------------------------------------------
// Host-side launch sequence
// ---------------------------------------------------------------------------
extern "C" void kernel_launch(void* const* d_in, const int* in_sizes, int n_in,
                              void* d_out, int out_size, void* d_ws,
                              size_t ws_size, hipStream_t stream) {
  (void)in_sizes; (void)n_in; (void)out_size; (void)ws_size;
  const float* u_in = (const float*)d_in[0];
  const int*   v_in = (const int*)d_in[1];
  const float* emb  = (const float*)d_in[2];
  const float* w1   = (const float*)d_in[3];
  const float* b1   = (const float*)d_in[4];
  const float* w2   = (const float*)d_in[5];
  const float* b2   = (const float*)d_in[6];
  const float* wih  = (const float*)d_in[7];
  const float* whh  = (const float*)d_in[8];
  const float* bih  = (const float*)d_in[9];
  const float* bhh  = (const float*)d_in[10];

  float* ws = (float*)d_ws;
  const size_t HP = (size_t)4 * NB * NC;           // 524288
  float* h0buf = ws;                               // [2][4][NB][NC]
  float* cbuf  = h0buf + 2 * HP;                   // [4][NB][NC]
  float* whhT  = cbuf + HP;                        // [528][2048]
  float* w1T   = whhT + (size_t)528 * 2048;        // [512][512]
  float* Hbuf  = w1T + (size_t)NC * NC;            // [NB][NC]
  float* WDp   = Hbuf + (size_t)NB * NC;           // [15][NC]
  float* A0v   = WDp + NFS * NC;                   // [NC]
  float* u_cur = A0v + NC;                         // [NB][16][16]
  int*   v_cur = (int*)(u_cur + NB * NL * NL);     // [NB][16][16]

  float* out_soft = (float*)d_out;                 // [NB][16][16][2]
  float* out_u = out_soft + NB * NL * NL * 2;      // [NB][16][16]
  float* out_v = out_u + NB * NL * NL;             // [NB][16][16]

  setup_kernel<<<dim3(4096), dim3(256), 0, stream>>>(
      u_in, v_in, h0buf, cbuf, u_cur, v_cur, out_soft, out_u, out_v);
  wd_kernel<<<dim3(16), dim3(256), 0, stream>>>(emb, w1, b1, WDp, A0v);
  transpose_kernel<<<dim3(256), dim3(256), 0, stream>>>(whh, whhT, 2048, 512);
  wih_t_kernel<<<dim3(128), dim3(256), 0, stream>>>(wih, whhT);
  transpose_kernel<<<dim3(64), dim3(256), 0, stream>>>(w1, w1T, 512, 512);

  for (int k = 0; k < 9; k++) {
    if (k > 0) {
      int e = k - 1;
      int col0 = (e % 3 == 0) ? 4 : ((e % 3 == 1) ? 8 : 0);
      lstm_event_kernel<<<dim3(768), dim3(256), 0, stream>>>(
          u_cur, whhT, bih, bhh,
          h0buf + (size_t)(e & 1) * HP,
          h0buf + (size_t)((e & 1) ^ 1) * HP, cbuf, col0);
    }
    w1h0_kernel<<<dim3(512), dim3(64), 0, stream>>>(
        h0buf + (size_t)(k & 1) * HP + (size_t)(k / 3) * NB * NC, w1T, Hbuf);
    pixel_kernel<<<dim3(256), dim3(64), 0, stream>>>(
        WDp, A0v, Hbuf, w2, b2, u_cur, v_cur, out_soft, out_u, out_v,
        (k / 3) * 4, (k % 3) * 4, k * 16);
  }
}

// Round 5
// 704.360 us; speedup vs baseline: 2.0806x; 2.0806x over previous
//
#include <hip/hip_runtime.h>
#include <cstdint>
#include <cstddef>

// ---------------------------------------------------------------------------
// Problem constants
// ---------------------------------------------------------------------------
constexpr int NB = 256;   // batch
constexpr int NC = 512;   // c_length
constexpr int NL = 16;    // lattice side
constexpr int NFS = 15;   // neighborhood size

#define PARTITIONABLE 1

// ---------------------------------------------------------------------------
// Threefry2x32-20 (JAX-compatible), usable at compile time and on device
// ---------------------------------------------------------------------------
struct TFOut { uint32_t a, b; };

__host__ __device__ constexpr uint32_t rotl32(uint32_t x, int d) {
  return (x << d) | (x >> (32 - d));
}

__host__ __device__ constexpr TFOut tf2x32(uint32_t k0, uint32_t k1,
                                           uint32_t x0, uint32_t x1) {
  uint32_t k2 = k0 ^ k1 ^ 0x1BD11BDAu;
  x0 += k0; x1 += k1;
  const int R0[4] = {13, 15, 26, 6};
  const int R1[4] = {17, 29, 16, 24};
  for (int i = 0; i < 4; i++) { x0 += x1; x1 = rotl32(x1, R0[i]); x1 ^= x0; }
  x0 += k1; x1 += k2 + 1u;
  for (int i = 0; i < 4; i++) { x0 += x1; x1 = rotl32(x1, R1[i]); x1 ^= x0; }
  x0 += k2; x1 += k0 + 2u;
  for (int i = 0; i < 4; i++) { x0 += x1; x1 = rotl32(x1, R0[i]); x1 ^= x0; }
  x0 += k0; x1 += k1 + 3u;
  for (int i = 0; i < 4; i++) { x0 += x1; x1 = rotl32(x1, R1[i]); x1 ^= x0; }
  x0 += k1; x1 += k2 + 4u;
  for (int i = 0; i < 4; i++) { x0 += x1; x1 = rotl32(x1, R0[i]); x1 ^= x0; }
  x0 += k2; x1 += k0 + 5u;
  return TFOut{x0, x1};
}

struct SubKeys { uint32_t v[288]; };

constexpr SubKeys make_subkeys() {
  SubKeys s{};
  uint32_t k0 = 0u, k1 = 1234u;
  for (int t = 0; t < 144; t++) {
#if PARTITIONABLE
    TFOut nk = tf2x32(k0, k1, 0u, 0u);
    TFOut sk = tf2x32(k0, k1, 0u, 1u);
    s.v[2 * t] = sk.a; s.v[2 * t + 1] = sk.b;
    k0 = nk.a; k1 = nk.b;
#else
    TFOut p0 = tf2x32(k0, k1, 0u, 2u);
    TFOut p1 = tf2x32(k0, k1, 1u, 3u);
    s.v[2 * t] = p0.b; s.v[2 * t + 1] = p1.b;
    k0 = p0.a; k1 = p1.a;
#endif
  }
  return s;
}

__constant__ SubKeys SUBKEYS = make_subkeys();

__device__ __forceinline__ float gumbel_from_bits(uint32_t bits) {
  uint32_t ub = (bits >> 9) | 0x3f800000u;
  float f = __uint_as_float(ub) - 1.0f;
  float u = (f == 0.0f) ? 1.17549435e-38f : f;
  float inner = logf(u);
  float outer = logf(-inner);
  return -outer;
}

// ---------------------------------------------------------------------------
// Kernel 0: init workspace + outputs
// ---------------------------------------------------------------------------
__global__ __launch_bounds__(256) void setup_kernel(
    const float* __restrict__ u_in, const int* __restrict__ v_in,
    float* __restrict__ h0buf, float* __restrict__ cbuf,
    float* __restrict__ u_cur, int* __restrict__ v_cur,
    float* __restrict__ out_soft, float* __restrict__ out_u,
    float* __restrict__ out_v) {
  int idx = blockIdx.x * 256 + threadIdx.x;
  h0buf[idx] = 0.0f;                         // 2 parities x [4][NB][NC]
  if (idx < 3 * NB * NC) cbuf[idx] = 0.0f;   // lstm cell state, 3 sectors
  if (idx < NB * NL * NL) {
    float uv = u_in[idx];
    int vv = v_in[idx];
    u_cur[idx] = uv;
    v_cur[idx] = vv;
    out_u[idx] = uv;
    out_v[idx] = (float)vv;
  }
  if (idx < NB * NL * NL * 2) out_soft[idx] = 0.0f;
}

// ---------------------------------------------------------------------------
// Kernel 1: WD[n][c] = W1 · (emb[n,1]-emb[n,0]);  A0 = W1 · Σ emb[n,0] + b1
// ---------------------------------------------------------------------------
__global__ __launch_bounds__(256) void wd_kernel(
    const float* __restrict__ emb, const float* __restrict__ w1,
    const float* __restrict__ b1, float* __restrict__ WD,
    float* __restrict__ A0v) {
  __shared__ double dvec[NC];
  int n = blockIdx.x, tid = threadIdx.x;
  for (int k = tid; k < NC; k += 256) {
    if (n < NFS) {
      dvec[k] = (double)emb[(n * 2 + 1) * NC + k] - (double)emb[(n * 2) * NC + k];
    } else {
      double s = 0.0;
      for (int nn = 0; nn < NFS; nn++) s += (double)emb[(nn * 2) * NC + k];
      dvec[k] = s;
    }
  }
  __syncthreads();
  for (int c = tid; c < NC; c += 256) {
    double acc = 0.0;
    const float* wrow = w1 + (size_t)c * NC;
    for (int k = 0; k < NC; k++) acc += dvec[k] * (double)wrow[k];
    if (n < NFS) WD[n * NC + c] = (float)acc;
    else         A0v[c] = (float)(acc + (double)b1[c]);
  }
}

// ---------------------------------------------------------------------------
// Kernel 2a: LSTM GEMM, split-K=2 (round-2 LDS-tiled structure).
// kz=0: k in [0,256); kz=1: k in [256,512) plus the 16-k uv@wih^T term.
// Writes bias-free partials gpart[kz][768][2048].
// grid = 768 blocks (kz = bx&1, tile id = bx>>1) -> 3 blocks/CU.
// ---------------------------------------------------------------------------
__global__ __launch_bounds__(256) void lstm_gemm_kernel(
    const float* __restrict__ u_cur, const float* __restrict__ whh,
    const float* __restrict__ wih, const float* __restrict__ h_in,
    float* __restrict__ gpart, int col0) {
  int bx = blockIdx.x;
  int kz = bx & 1;
  int bxx = bx >> 1;                 // [0,384)
  int s = bxx >> 7;
  int bt = (bxx >> 5) & 3;
  int ct = bxx & 31;
  int tid = threadIdx.x, tn = tid & 15, tb = tid >> 4;

  __shared__ float hs[64][36];   // 64 rows x 32 k (pad 36)
  __shared__ float wt[64][36];   // 64 (col,gate) x 32 k
  __shared__ float uvs[64][16];

  if (kz == 1) {
    for (int idx = tid; idx < 1024; idx += 256) {
      int row = idx >> 4, nn = idx & 15;
      int b = bt * 64 + row;
      uvs[row][nn] = u_cur[b * 256 + (s * 4 + (nn >> 2)) * 16 + col0 + (nn & 3)];
    }
  }

  float acc[4][4] = {};
  const float* hbase = h_in + ((size_t)s * NB + bt * 64) * NC;
  int kbase = kz * 256;

  for (int kc = 0; kc < 8; kc++) {
    int k0 = kbase + kc * 32;
    __syncthreads();
    for (int t = 0; t < 2; t++) {
      int idx = tid + t * 256;            // [0,512)
      int row = idx >> 3, kk4 = idx & 7;
      *(float4*)&hs[row][kk4 * 4] =
          *(const float4*)(hbase + (size_t)row * NC + k0 + kk4 * 4);
      int wrow = ((row >> 4) * NC) + ct * 16 + (row & 15); // gate*512 + col
      *(float4*)&wt[row][kk4 * 4] =
          *(const float4*)(whh + (size_t)wrow * NC + k0 + kk4 * 4);
    }
    __syncthreads();
#pragma unroll
    for (int kk4 = 0; kk4 < 8; kk4++) {
      float4 hv[4], wv[4];
#pragma unroll
      for (int i = 0; i < 4; i++) hv[i] = *(float4*)&hs[tb * 4 + i][kk4 * 4];
#pragma unroll
      for (int g = 0; g < 4; g++) wv[g] = *(float4*)&wt[tn + 16 * g][kk4 * 4];
#pragma unroll
      for (int i = 0; i < 4; i++)
#pragma unroll
        for (int g = 0; g < 4; g++)
          acc[i][g] += hv[i].x * wv[g].x + hv[i].y * wv[g].y +
                       hv[i].z * wv[g].z + hv[i].w * wv[g].w;
    }
  }

  int c = ct * 16 + tn;
  float* gp = gpart + (size_t)kz * 768 * 2048;
#pragma unroll
  for (int i = 0; i < 4; i++) {
    int row = tb * 4 + i, b = bt * 64 + row;
    int grow = s * 256 + b;
#pragma unroll
    for (int g = 0; g < 4; g++) {
      float v = acc[i][g];
      if (kz == 1) {
        int nidx = g * NC + c;
        const float* wrow = wih + (size_t)nidx * 16;
        float extra = 0.0f;
#pragma unroll
        for (int nn = 0; nn < 16; nn++) extra += uvs[row][nn] * wrow[nn];
        v += extra;
      }
      gp[(size_t)grow * 2048 + g * 512 + c] = v;
    }
  }
}

// ---------------------------------------------------------------------------
// Kernel 2b: reduce split-K partials + bias + LSTM nonlinearity.
// 768 rows x 512 cols; grid = 1536 x 256.
// ---------------------------------------------------------------------------
__global__ __launch_bounds__(256) void lstm_gates_kernel(
    const float* __restrict__ gpart, const float* __restrict__ bih,
    const float* __restrict__ bhh, float* __restrict__ h_out,
    float* __restrict__ cbuf) {
  int idx = blockIdx.x * 256 + threadIdx.x;   // [0, 393216)
  int row = idx >> 9, c = idx & 511;
  const float* gp0 = gpart;
  const float* gp1 = gpart + (size_t)768 * 2048;
  size_t base = (size_t)row * 2048 + c;
  float gv[4];
#pragma unroll
  for (int g = 0; g < 4; g++) {
    int nidx = g * 512 + c;
    gv[g] = gp0[base + g * 512] + gp1[base + g * 512] + bih[nidx] + bhh[nidx];
  }
  size_t off = (size_t)row * NC + c;
  float c_old = cbuf[off];
  float sig_i = 1.0f / (1.0f + expf(-gv[0]));
  float sig_f = 1.0f / (1.0f + expf(-gv[1]));
  float tg    = tanhf(gv[2]);
  float sig_o = 1.0f / (1.0f + expf(-gv[3]));
  float cn = sig_f * c_old + sig_i * tg;
  float hn = sig_o * tanhf(cn);
  cbuf[off] = cn;
  h_out[off] = hn;
}

// ---------------------------------------------------------------------------
// Kernel 3: Hpart[ks][b][c] partials of H = W1 · h0 (round-2 LDS version)
// grid = 8(ks,K=64 each) * 4(bt) * 8(ct) = 256 blocks, 256 threads.
// ---------------------------------------------------------------------------
__global__ __launch_bounds__(256) void w1h0_kernel(
    const float* __restrict__ h_in,   // [NB][NC] slice for (parity, s=i)
    const float* __restrict__ w1, float* __restrict__ Hpart) {
  int bx = blockIdx.x;
  int ks = bx >> 5;
  int bt = (bx >> 3) & 3;
  int ct = bx & 7;
  int tid = threadIdx.x, tn = tid & 15, tb = tid >> 4;

  __shared__ float hs[64][36];
  __shared__ float wt[64][36];
  float acc[4][4] = {};
  const float* hbase = h_in + (size_t)(bt * 64) * NC;

  for (int kc = 0; kc < 2; kc++) {
    int k0 = ks * 64 + kc * 32;
    __syncthreads();
    for (int t = 0; t < 2; t++) {
      int idx = tid + t * 256;
      int row = idx >> 3, kk4 = idx & 7;
      *(float4*)&hs[row][kk4 * 4] =
          *(const float4*)(hbase + (size_t)row * NC + k0 + kk4 * 4);
      int wrow = ct * 64 + row;
      *(float4*)&wt[row][kk4 * 4] =
          *(const float4*)(w1 + (size_t)wrow * NC + k0 + kk4 * 4);
    }
    __syncthreads();
#pragma unroll
    for (int kk4 = 0; kk4 < 8; kk4++) {
      float4 hv[4], wv[4];
#pragma unroll
      for (int i = 0; i < 4; i++) hv[i] = *(float4*)&hs[tb * 4 + i][kk4 * 4];
#pragma unroll
      for (int j = 0; j < 4; j++) wv[j] = *(float4*)&wt[tn + 16 * j][kk4 * 4];
#pragma unroll
      for (int i = 0; i < 4; i++)
#pragma unroll
        for (int j = 0; j < 4; j++)
          acc[i][j] += hv[i].x * wv[j].x + hv[i].y * wv[j].y +
                       hv[i].z * wv[j].z + hv[i].w * wv[j].w;
    }
  }
#pragma unroll
  for (int i = 0; i < 4; i++) {
    int b = bt * 64 + tb * 4 + i;
#pragma unroll
    for (int j = 0; j < 4; j++) {
      int cidx = ct * 64 + tn + 16 * j;
      Hpart[((size_t)ks * NB + b) * NC + cidx] = acc[i][j];
    }
  }
}

// ---------------------------------------------------------------------------
// Kernel 4: 16-pixel autoregressive block (round-2 register version,
// 8-partial Hpart sum).
// ---------------------------------------------------------------------------
__global__ __launch_bounds__(64) void pixel_kernel(
    const float* __restrict__ WD, const float* __restrict__ A0v,
    const float* __restrict__ Hpart, const float* __restrict__ w2,
    const float* __restrict__ b2, float* __restrict__ u_cur,
    int* __restrict__ v_cur, float* __restrict__ out_soft,
    float* __restrict__ out_u, float* __restrict__ out_v,
    int si, int sj, int t_base) {
  int b = blockIdx.x, lane = threadIdx.x;
  __shared__ float gum[32];

  int widx = (lane < 49) ? lane : 48;
  int vv = v_cur[b * 256 + (si + 1 + widx / 7) * 16 + (sj + 1 + widx % 7)];
  unsigned long long mask = __ballot((lane < 49) && (vv != 0));

  if (lane < 32) {
    int t = t_base + (lane >> 1);
    uint32_t sk0 = SUBKEYS.v[2 * t], sk1 = SUBKEYS.v[2 * t + 1];
    uint32_t bits;
#if PARTITIONABLE
    TFOut o = tf2x32(sk0, sk1, 0u, (uint32_t)(2 * b + (lane & 1)));
    bits = o.a ^ o.b;
#else
    uint32_t f = (uint32_t)(2 * b + (lane & 1));
    if (f < 256u) { TFOut o = tf2x32(sk0, sk1, f, f + 256u); bits = o.a; }
    else          { TFOut o = tf2x32(sk0, sk1, f - 256u, f); bits = o.b; }
#endif
    gum[lane] = gumbel_from_bits(bits);
  }

  float wdreg[NFS][8];
#pragma unroll
  for (int n = 0; n < NFS; n++)
#pragma unroll
    for (int r = 0; r < 8; r++) wdreg[n][r] = WD[n * NC + lane + 64 * r];

  float w2r0[8], w2r1[8];
#pragma unroll
  for (int r = 0; r < 8; r++) {
    w2r0[r] = w2[lane + 64 * r];
    w2r1[r] = w2[NC + lane + 64 * r];
  }
  double b20 = (double)b2[0], b21 = (double)b2[1];

  float base[8];
#pragma unroll
  for (int r = 0; r < 8; r++) {
    int c = lane + 64 * r;
    float v = A0v[c];
#pragma unroll
    for (int ks = 0; ks < 8; ks++) v += Hpart[((size_t)ks * NB + b) * NC + c];
    base[r] = v;
  }
  __syncthreads();

#pragma unroll 1
  for (int ii = 0; ii < 4; ii++) {
#pragma unroll 1
    for (int jj = 0; jj < 4; jj++) {
      int bofs = ii * 7 + jj;
      float acc[8];
#pragma unroll
      for (int r = 0; r < 8; r++) acc[r] = base[r];
#pragma unroll
      for (int n = 0; n < NFS; n++) {
        const int OFF = (n / 4) * 7 + (n % 4);
        float pf = (float)((unsigned)((mask >> (bofs + OFF)) & 1ull));
#pragma unroll
        for (int r = 0; r < 8; r++) acc[r] = fmaf(pf, wdreg[n][r], acc[r]);
      }
      double d0 = 0.0, d1 = 0.0;
#pragma unroll
      for (int r = 0; r < 8; r++) {
        float z = fmaxf(acc[r], 0.0f);
        d0 += (double)z * (double)w2r0[r];
        d1 += (double)z * (double)w2r1[r];
      }
#pragma unroll
      for (int off = 32; off > 0; off >>= 1) {
        d0 += __shfl_xor(d0, off, 64);
        d1 += __shfl_xor(d1, off, 64);
      }
      float r0 = (float)(d0 + b20);
      float r1 = (float)(d1 + b21);
      float m = fmaxf(r0, r1);
      float s0 = r0 - m, s1 = r1 - m;
      float lse = logf(expf(s0) + expf(s1));
      float l0 = s0 - lse, l1 = s1 - lse;
      int pidx = ii * 4 + jj;
      float a0 = l0 + gum[2 * pidx];
      float a1 = l1 + gum[2 * pidx + 1];
      int samp = (a1 > a0) ? 1 : 0;
      int tbit = bofs + 24;
      mask = (mask & ~(1ull << tbit)) | ((unsigned long long)samp << tbit);
      if (lane == 0) {
        int pr = si + ii + 4, pc = sj + jj + 4;
        size_t so = ((size_t)(b * 16 + pr) * 16 + pc) * 2;
        out_soft[so] = l0;
        out_soft[so + 1] = l1;
        int po = b * 256 + pr * 16 + pc;
        float fs = (float)samp;
        u_cur[po] = fs;
        v_cur[po] = samp;
        out_u[po] = fs;
        out_v[po] = fs;
      }
    }
  }
}

// ---------------------------------------------------------------------------
// Host-side launch sequence
// ---------------------------------------------------------------------------
extern "C" void kernel_launch(void* const* d_in, const int* in_sizes, int n_in,
                              void* d_out, int out_size, void* d_ws,
                              size_t ws_size, hipStream_t stream) {
  (void)in_sizes; (void)n_in; (void)out_size; (void)ws_size;
  const float* u_in = (const float*)d_in[0];
  const int*   v_in = (const int*)d_in[1];
  const float* emb  = (const float*)d_in[2];
  const float* w1   = (const float*)d_in[3];
  const float* b1   = (const float*)d_in[4];
  const float* w2   = (const float*)d_in[5];
  const float* b2   = (const float*)d_in[6];
  const float* wih  = (const float*)d_in[7];
  const float* whh  = (const float*)d_in[8];
  const float* bih  = (const float*)d_in[9];
  const float* bhh  = (const float*)d_in[10];

  float* ws = (float*)d_ws;
  const size_t HP = (size_t)4 * NB * NC;           // 524288: h parity stride
  float* h0buf = ws;                               // [2][4][NB][NC]
  float* cbuf  = h0buf + 2 * HP;                   // [3][NB][NC]
  float* gpart = cbuf + (size_t)3 * NB * NC;       // [2][768][2048]
  float* Hpart = gpart + (size_t)2 * 768 * 2048;   // [8][NB][NC]
  float* WDp   = Hpart + (size_t)8 * NB * NC;      // [15][NC]
  float* A0v   = WDp + NFS * NC;                   // [NC]
  float* u_cur = A0v + NC;                         // [NB][16][16]
  int*   v_cur = (int*)(u_cur + NB * NL * NL);     // [NB][16][16]

  float* out_soft = (float*)d_out;                 // [NB][16][16][2]
  float* out_u = out_soft + NB * NL * NL * 2;      // [NB][16][16]
  float* out_v = out_u + NB * NL * NL;             // [NB][16][16]

  setup_kernel<<<dim3(4096), dim3(256), 0, stream>>>(
      u_in, v_in, h0buf, cbuf, u_cur, v_cur, out_soft, out_u, out_v);
  wd_kernel<<<dim3(16), dim3(256), 0, stream>>>(emb, w1, b1, WDp, A0v);

  for (int k = 0; k < 9; k++) {
    if (k > 0) {
      int e = k - 1;
      int col0 = (e % 3 == 0) ? 4 : ((e % 3 == 1) ? 8 : 0);
      lstm_gemm_kernel<<<dim3(768), dim3(256), 0, stream>>>(
          u_cur, whh, wih, h0buf + (size_t)(e & 1) * HP, gpart, col0);
      lstm_gates_kernel<<<dim3(1536), dim3(256), 0, stream>>>(
          gpart, bih, bhh, h0buf + (size_t)((e & 1) ^ 1) * HP, cbuf);
    }
    w1h0_kernel<<<dim3(256), dim3(256), 0, stream>>>(
        h0buf + (size_t)(k & 1) * HP + (size_t)(k / 3) * NB * NC, w1, Hpart);
    pixel_kernel<<<dim3(256), dim3(64), 0, stream>>>(
        WDp, A0v, Hpart, w2, b2, u_cur, v_cur, out_soft, out_u, out_v,
        (k / 3) * 4, (k % 3) * 4, k * 16);
  }
}